// Round 8
// baseline (276.367 us; speedup 1.0000x reference)
//
#include <hip/hip_runtime.h>
#include <math.h>

#define DIM 256
#define NROWS_TILE 128
#define SPLITS 8
#define NCAND SPLITS                // one wave owns each row: 1 slot per split
#define CODES_PER_SPLIT 1024        // K / SPLITS, K = 8192
#define CCH 32                      // codes per chunk-pair (two k-half sub-phases)
#define NPH 64                      // sub-phases = 32 chunk-pairs x 2 k-halves
#define NBUF 3
#define BUF_F16 8192                // 16 KB: [Bh: ch0 4frag, ch1 4frag | Bl: same]

typedef __attribute__((ext_vector_type(8))) _Float16 f16x8;
typedef __attribute__((ext_vector_type(4))) _Float16 f16x4;
typedef __attribute__((ext_vector_type(4))) float f32x4;

__device__ __forceinline__ void gload16(const void* g, void* l) {
    __builtin_amdgcn_global_load_lds(
        (const __attribute__((address_space(1))) void*)g,
        (__attribute__((address_space(3))) void*)l, 16, 0, 0);
}

__device__ __forceinline__ float waveReduceSum(float v) {
#pragma unroll
    for (int off = 32; off >= 1; off >>= 1) v += __shfl_xor(v, off, 64);
    return v;
}

// ---------- prep: row-l2norm + split-f16 encode (hi + lo*2048) ----------
__global__ __launch_bounds__(256) void k_prep(const float* __restrict__ in,
        _Float16* __restrict__ hi, _Float16* __restrict__ lo,
        float* __restrict__ norms, int nrows)
{
    const int w = threadIdx.x >> 6, lane = threadIdx.x & 63;
    const int r = blockIdx.x * 4 + w;
    if (r >= nrows) return;
    f32x4 v = *(const f32x4*)&in[(size_t)r * DIM + lane * 4];
    float ss = waveReduceSum(v[0]*v[0] + v[1]*v[1] + v[2]*v[2] + v[3]*v[3]);
    const float n = fmaxf(sqrtf(ss), 1e-12f);
    if (norms != nullptr && lane == 0) norms[r] = n;
    f32x4 f;
    f[0] = v[0] / n; f[1] = v[1] / n; f[2] = v[2] / n; f[3] = v[3] / n;
    f16x4 h, l;
#pragma unroll
    for (int c = 0; c < 4; ++c) {
        h[c] = (_Float16)f[c];
        l[c] = (_Float16)((f[c] - (float)h[c]) * 2048.0f);
    }
    *(f16x4*)&hi[(size_t)r * DIM + lane * 4] = h;
    *(f16x4*)&lo[(size_t)r * DIM + lane * 4] = l;
}

// ---------- main: split-f16 MFMA GEMM-BT, A in registers ----------
// grid: (N/128 row tiles, SPLITS). Block 256 thr = 4 waves; wave owns 32 rows
// x full K=256 in regs. Sub-phase = 32 codes x 128 k = 16 KB B-chunk, ring-3,
// counted vmcnt(4). Wave-pair STAGGER: waves 0-1 compute col-half 0 then 1,
// waves 2-3 the reverse -> half the waves ds_read while half MFMA (overlap).
// s_setprio(1) around each MFMA cluster (T5; role diversity now exists).
__global__ __launch_bounds__(256, 2) void k_gemm(
    const _Float16* __restrict__ fnh, const _Float16* __restrict__ fnl,
    const _Float16* __restrict__ enh, const _Float16* __restrict__ enl,
    float* __restrict__ cand_val, int* __restrict__ cand_idx)
{
    // buf (f16 units): [Bh: (ch*4+kc)*512 | Bl: +4096]; slot lane*8 =
    // en?[(cb+ch*16+(lane&15))*256 + kh*128 + kc*32 + (lane>>4)*8]
    __shared__ _Float16 smem[NBUF][BUF_F16];   // 3 x 16 KB

    const int t = threadIdx.x;
    const int w = t >> 6, lane = t & 63;
    const int rbase = blockIdx.x * NROWS_TILE;
    const int cbase = blockIdx.y * CODES_PER_SPLIT;
    const int koff = (lane >> 4) * 8;

    // ---- A panel into registers: wave w rows rbase+w*32 .. +31, full K ----
    f16x8 Ah[2][8], Al[2][8];
    {
        const size_t arow = (size_t)(rbase + w * 32 + (lane & 15)) * DIM;
#pragma unroll
        for (int i = 0; i < 2; ++i)
#pragma unroll
            for (int kc = 0; kc < 8; ++kc) {
                Ah[i][kc] = *(const f16x8*)&fnh[arow + (size_t)i * 16 * DIM + kc * 32 + koff];
                Al[i][kc] = *(const f16x8*)&fnl[arow + (size_t)i * 16 * DIM + kc * 32 + koff];
            }
    }
    asm volatile("s_waitcnt vmcnt(0)" ::: "memory");   // A done; vmcnt clean

    // staging roles: wave w stages mat = w>>1 (0=hi,1=lo), col-half = w&1
    const _Float16* const bsrc = (w < 2) ? enh : enl;
    const int ch_st = w & 1;
    const int ldsoff = (w >> 1) * 4096 + ch_st * 2048;

    auto STAGE = [&](int p, int buf) {
        const int cb = cbase + (p >> 1) * CCH;
        const _Float16* g0 = bsrc + (size_t)(cb + ch_st * 16 + (lane & 15)) * DIM
                                  + (p & 1) * 128 + koff;
        _Float16* l0 = &smem[buf][ldsoff];
#pragma unroll
        for (int q = 0; q < 4; ++q)
            gload16(g0 + q * 32, l0 + q * 512);
    };

    float bestv[2][4];
    int   bestc[2][4];
#pragma unroll
    for (int i = 0; i < 2; ++i)
#pragma unroll
        for (int rg = 0; rg < 4; ++rg) { bestv[i][rg] = -2.0f; bestc[i][rg] = 0; }

    f32x4 acc0[2][2], acc1a[2][2], acc1b[2][2];   // [ch][i]

    // prologue: two sub-phase chunks in flight
    STAGE(0, 0);
    STAGE(1, 1);

    int cur = 0;

#define DO_CH(CHX, KH) do {                                                              \
        f16x8 bh[4], bl[4];                                                              \
        _Pragma("unroll")                                                                \
        for (int kc = 0; kc < 4; ++kc) {                                                 \
            bh[kc] = *(const f16x8*)(bufp + (CHX) * 2048 + kc * 512 + lane * 8);         \
            bl[kc] = *(const f16x8*)(bufp + 4096 + (CHX) * 2048 + kc * 512 + lane * 8);  \
        }                                                                                \
        __builtin_amdgcn_s_setprio(1);                                                   \
        _Pragma("unroll")                                                                \
        for (int kc = 0; kc < 4; ++kc) {                                                 \
            _Pragma("unroll")                                                            \
            for (int i = 0; i < 2; ++i) {                                                \
                acc0[CHX][i]  = __builtin_amdgcn_mfma_f32_16x16x32_f16(                  \
                    Ah[i][(KH) * 4 + kc], bh[kc], acc0[CHX][i], 0, 0, 0);                \
                acc1a[CHX][i] = __builtin_amdgcn_mfma_f32_16x16x32_f16(                  \
                    Ah[i][(KH) * 4 + kc], bl[kc], acc1a[CHX][i], 0, 0, 0);               \
                acc1b[CHX][i] = __builtin_amdgcn_mfma_f32_16x16x32_f16(                  \
                    Al[i][(KH) * 4 + kc], bh[kc], acc1b[CHX][i], 0, 0, 0);               \
            }                                                                            \
        }                                                                                \
        __builtin_amdgcn_s_setprio(0);                                                   \
    } while (0)

#define SUBPHASE(KH, P) do {                                                             \
        if ((P) == NPH - 1) asm volatile("s_waitcnt vmcnt(0)" ::: "memory");             \
        else                asm volatile("s_waitcnt vmcnt(4)" ::: "memory");             \
        __builtin_amdgcn_s_barrier();                                                    \
        if ((P) + 2 < NPH) {                                                             \
            int sb = cur - 1; if (sb < 0) sb += NBUF;                                    \
            STAGE((P) + 2, sb);                                                          \
        }                                                                                \
        const _Float16* bufp = &smem[cur][0];                                            \
        if ((KH) == 0) {                                                                 \
            _Pragma("unroll")                                                            \
            for (int c_ = 0; c_ < 2; ++c_)                                               \
            { _Pragma("unroll")                                                          \
              for (int i_ = 0; i_ < 2; ++i_) {                                           \
                acc0[c_][i_]  = (f32x4){0.f, 0.f, 0.f, 0.f};                             \
                acc1a[c_][i_] = (f32x4){0.f, 0.f, 0.f, 0.f};                             \
                acc1b[c_][i_] = (f32x4){0.f, 0.f, 0.f, 0.f};                             \
            } }                                                                          \
        }                                                                                \
        if (w < 2) { DO_CH(0, KH); DO_CH(1, KH); }                                       \
        else       { DO_CH(1, KH); DO_CH(0, KH); }                                       \
        if ((KH) == 1) {                                                                 \
            _Pragma("unroll")                                                            \
            for (int c_ = 0; c_ < 2; ++c_)                                               \
            { _Pragma("unroll")                                                          \
              for (int i_ = 0; i_ < 2; ++i_)                                             \
              { _Pragma("unroll")                                                        \
                for (int rg = 0; rg < 4; ++rg) {                                         \
                    const float vv = acc0[c_][i_][rg] +                                  \
                        (acc1a[c_][i_][rg] + acc1b[c_][i_][rg]) * (1.0f / 2048.0f);      \
                    const int cd = cb + c_ * 16;                                         \
                    if (vv > bestv[i_][rg] ||                                            \
                        (vv == bestv[i_][rg] && cd < bestc[i_][rg])) {                   \
                        bestv[i_][rg] = vv; bestc[i_][rg] = cd;                          \
                    }                                                                    \
                } } }                                                                    \
        }                                                                                \
        cur = (cur == NBUF - 1) ? 0 : cur + 1;                                           \
    } while (0)

#pragma unroll 1
    for (int cbi = 0; cbi < 32; ++cbi) {
        const int cb = cbase + cbi * CCH;
        SUBPHASE(0, cbi * 2);
        SUBPHASE(1, cbi * 2 + 1);
    }
#undef DO_CH
#undef SUBPHASE

    // final cross-lane argmax (width 16), min-index tie-break
#pragma unroll
    for (int i = 0; i < 2; ++i)
#pragma unroll
        for (int rg = 0; rg < 4; ++rg) {
            float bv = bestv[i][rg];
            int bix = bestc[i][rg] + (lane & 15);
#pragma unroll
            for (int off = 1; off < 16; off <<= 1) {
                const float ov = __shfl_xor(bv, off, 16);
                const int oi = __shfl_xor(bix, off, 16);
                if (ov > bv || (ov == bv && oi < bix)) { bv = ov; bix = oi; }
            }
            if ((lane & 15) == 0) {
                const int r = rbase + w * 32 + i * 16 + (lane >> 4) * 4 + rg;
                cand_val[(size_t)r * NCAND + blockIdx.y] = bv;
                cand_idx[(size_t)r * NCAND + blockIdx.y] = bix;
            }
        }
}

// ---------- merge splits + gather quantize + scatter embed_sum ----------
__global__ __launch_bounds__(256) void k_merge(
    const float* __restrict__ x, const float* __restrict__ embed,
    const float* __restrict__ cand_val, const int* __restrict__ cand_idx,
    const float* __restrict__ xnorm,
    float* __restrict__ quantize, float* __restrict__ ind_out,
    float* __restrict__ embed_sum, float* __restrict__ bins)
{
    const int w = threadIdx.x >> 6, lane = threadIdx.x & 63;
    const int r = blockIdx.x * 4 + w;
    float v = -3e30f; int ix = 0x7fffffff;
    if (lane < NCAND) {
        v = cand_val[(size_t)r * NCAND + lane];
        ix = cand_idx[(size_t)r * NCAND + lane];
    }
#pragma unroll
    for (int off = 1; off < 8; off <<= 1) {
        const float ov = __shfl_xor(v, off, 8);
        const int oi = __shfl_xor(ix, off, 8);
        if (ov > v || (ov == v && oi < ix)) { v = ov; ix = oi; }
    }
    ix = __shfl(ix, 0, 64);
    if (lane == 0) {
        ind_out[r] = (float)ix;
        atomicAdd(&bins[ix], 1.0f);
    }
    f32x4 e = *(const f32x4*)&embed[(size_t)ix * DIM + lane * 4];
    *(f32x4*)&quantize[(size_t)r * DIM + lane * 4] = e;
    f32x4 xv = *(const f32x4*)&x[(size_t)r * DIM + lane * 4];
    const float n = xnorm[r];
    atomicAdd(&embed_sum[(size_t)ix * DIM + lane * 4 + 0], xv[0] / n);
    atomicAdd(&embed_sum[(size_t)ix * DIM + lane * 4 + 1], xv[1] / n);
    atomicAdd(&embed_sum[(size_t)ix * DIM + lane * 4 + 2], xv[2] / n);
    atomicAdd(&embed_sum[(size_t)ix * DIM + lane * 4 + 3], xv[3] / n);
}

// ---------- EMA update (en recomputed inline) ----------
__global__ __launch_bounds__(256) void k_update(const float* __restrict__ embed,
    const float* __restrict__ embed_sum, const float* __restrict__ bins,
    float* __restrict__ embed_new, int K)
{
    const int w = threadIdx.x >> 6, lane = threadIdx.x & 63;
    const int k = blockIdx.x * 4 + w;
    if (k >= K) return;
    f32x4 e = *(const f32x4*)&embed[(size_t)k * DIM + lane * 4];
    float sse = waveReduceSum(e[0]*e[0] + e[1]*e[1] + e[2]*e[2] + e[3]*e[3]);
    const float ne = fmaxf(sqrtf(sse), 1e-12f);

    const float b = bins[k];
    const float bs = (b == 0.f) ? 1.f : b;
    f32x4 s = *(const f32x4*)&embed_sum[(size_t)k * DIM + lane * 4];
    f32x4 vv;
    vv[0] = s[0] / bs; vv[1] = s[1] / bs; vv[2] = s[2] / bs; vv[3] = s[3] / bs;
    float ssv = waveReduceSum(vv[0]*vv[0] + vv[1]*vv[1] + vv[2]*vv[2] + vv[3]*vv[3]);
    const float nv = fmaxf(sqrtf(ssv), 1e-12f);

    f32x4 o;
#pragma unroll
    for (int c = 0; c < 4; ++c) {
        const float norm_c = (b == 0.f) ? (e[c] / ne) : (vv[c] / nv);
        o[c] = 0.8f * e[c] + 0.2f * norm_c;
    }
    *(f32x4*)&embed_new[(size_t)k * DIM + lane * 4] = o;
}

extern "C" void kernel_launch(void* const* d_in, const int* in_sizes, int n_in,
                              void* d_out, int out_size, void* d_ws, size_t ws_size,
                              hipStream_t stream) {
    const float* x = (const float*)d_in[0];
    const float* embed = (const float*)d_in[1];
    const int N = in_sizes[0] / DIM;   // 16384
    const int K = in_sizes[1] / DIM;   // 8192

    float* quantize  = (float*)d_out;
    float* ind_out   = quantize + (size_t)N * DIM;
    float* embed_new = ind_out + N;

    char* ws = (char*)d_ws;
    _Float16* fnh = (_Float16*)ws;                               // [0, 8M)
    _Float16* fnl = (_Float16*)(ws + (size_t)N * DIM * 2);       // [8M, 16M)
    _Float16* enh = (_Float16*)(ws + (size_t)N * DIM * 4);       // [16M, 20M)
    _Float16* enl = (_Float16*)(ws + (size_t)N * DIM * 4 + (size_t)K * DIM * 2);
    char* p = ws + (size_t)N * DIM * 4 + (size_t)K * DIM * 4;    // 24M
    float* xnorm    = (float*)p;                 p += (size_t)N * 4;
    float* cand_val = (float*)p;                 p += (size_t)N * NCAND * 4;
    int*   cand_idx = (int*)p;
    // embed_sum/bins alias fnh/fnl (dead after k_gemm)
    float* embed_sum = (float*)ws;               // K*DIM floats = 8 MB
    float* bins      = embed_sum + (size_t)K * DIM;

    k_prep<<<(N + 3) / 4, 256, 0, stream>>>(x, fnh, fnl, xnorm, N);
    k_prep<<<(K + 3) / 4, 256, 0, stream>>>(embed, enh, enl, nullptr, K);

    dim3 grid(N / NROWS_TILE, SPLITS);
    k_gemm<<<grid, 256, 0, stream>>>(fnh, fnl, enh, enl, cand_val, cand_idx);

    hipMemsetAsync(embed_sum, 0, ((size_t)K * DIM + K) * sizeof(float), stream);

    k_merge<<<(N + 3) / 4, 256, 0, stream>>>(x, embed, cand_val, cand_idx, xnorm,
                                             quantize, ind_out, embed_sum, bins);
    k_update<<<(K + 3) / 4, 256, 0, stream>>>(embed, embed_sum, bins, embed_new, K);
}

// Round 10
// 261.216 us; speedup vs baseline: 1.0580x; 1.0580x over previous
//
#include <hip/hip_runtime.h>
#include <math.h>

#define DIM 256
#define NROWS_TILE 128
#define SPLITS 8
#define NCAND SPLITS                // one wave owns each row: 1 slot per split
#define CODES_PER_SPLIT 1024        // K / SPLITS, K = 8192
#define CCH 32                      // codes per phase (full K=256 staged)
#define NPH (CODES_PER_SPLIT / CCH) // 32 phases
#define BUF_F16 16384               // 32 KB: [Bh: ch(2) x kc(8) frags x 512 | Bl: +8192]

typedef __attribute__((ext_vector_type(8))) _Float16 f16x8;
typedef __attribute__((ext_vector_type(4))) _Float16 f16x4;
typedef __attribute__((ext_vector_type(4))) float f32x4;

__device__ __forceinline__ void gload16(const void* g, void* l) {
    __builtin_amdgcn_global_load_lds(
        (const __attribute__((address_space(1))) void*)g,
        (__attribute__((address_space(3))) void*)l, 16, 0, 0);
}

__device__ __forceinline__ float waveReduceSum(float v) {
#pragma unroll
    for (int off = 32; off >= 1; off >>= 1) v += __shfl_xor(v, off, 64);
    return v;
}

// ---------- prep: row-l2norm + split-f16 encode (hi + lo*2048) ----------
__global__ __launch_bounds__(256) void k_prep(const float* __restrict__ in,
        _Float16* __restrict__ hi, _Float16* __restrict__ lo,
        float* __restrict__ norms, int nrows)
{
    const int w = threadIdx.x >> 6, lane = threadIdx.x & 63;
    const int r = blockIdx.x * 4 + w;
    if (r >= nrows) return;
    f32x4 v = *(const f32x4*)&in[(size_t)r * DIM + lane * 4];
    float ss = waveReduceSum(v[0]*v[0] + v[1]*v[1] + v[2]*v[2] + v[3]*v[3]);
    const float n = fmaxf(sqrtf(ss), 1e-12f);
    if (norms != nullptr && lane == 0) norms[r] = n;
    f32x4 f;
    f[0] = v[0] / n; f[1] = v[1] / n; f[2] = v[2] / n; f[3] = v[3] / n;
    f16x4 h, l;
#pragma unroll
    for (int c = 0; c < 4; ++c) {
        h[c] = (_Float16)f[c];
        l[c] = (_Float16)((f[c] - (float)h[c]) * 2048.0f);
    }
    *(f16x4*)&hi[(size_t)r * DIM + lane * 4] = h;
    *(f16x4*)&lo[(size_t)r * DIM + lane * 4] = l;
}

// ---------- main: split-f16 MFMA GEMM-BT, A in registers ----------
// grid: (N/128 row tiles, SPLITS). Block 256 thr = 4 waves; wave owns 32 rows
// x full K=256 in regs (Ah/Al = 128 VGPR). Phase = 32 codes x K=256 x {hi,lo}
// = 32 KB chunk, ring-2 (64 KB LDS). Publish protocol (R7-proven):
//   iter c: s_waitcnt vmcnt(0)  [own chunk-c loads landed -> publishable]
//           s_barrier            [all waves' chunk-c loads visible; buf^1 retired]
//           stage(c+1 -> buf^1)  [full compute phase (~3600cy) to land >> 900cy lat]
//           compute(chunk c)
// acc init via zero-C first MFMA; incremental stage pointers; strict-> argmax.
__global__ __launch_bounds__(256, 2) void k_gemm(
    const _Float16* __restrict__ fnh, const _Float16* __restrict__ fnl,
    const _Float16* __restrict__ enh, const _Float16* __restrict__ enl,
    float* __restrict__ cand_val, int* __restrict__ cand_idx)
{
    // buf (f16 units): Bh frag (ch*8+kc)*512, Bl at +8192; slot lane*8 =
    // en?[(cb+ch*16+(lane&15))*256 + kc*32 + (lane>>4)*8]
    __shared__ _Float16 smem[2][BUF_F16];   // 2 x 32 KB

    const int t = threadIdx.x;
    const int w = t >> 6, lane = t & 63;
    const int rbase = blockIdx.x * NROWS_TILE;
    const int cbase = blockIdx.y * CODES_PER_SPLIT;
    const int koff = (lane >> 4) * 8;

    // ---- A panel into registers: wave w rows rbase+w*32 .. +31, full K ----
    f16x8 Ah[2][8], Al[2][8];
    {
        const size_t arow = (size_t)(rbase + w * 32 + (lane & 15)) * DIM;
#pragma unroll
        for (int i = 0; i < 2; ++i)
#pragma unroll
            for (int kc = 0; kc < 8; ++kc) {
                Ah[i][kc] = *(const f16x8*)&fnh[arow + (size_t)i * 16 * DIM + kc * 32 + koff];
                Al[i][kc] = *(const f16x8*)&fnl[arow + (size_t)i * 16 * DIM + kc * 32 + koff];
            }
    }
    asm volatile("s_waitcnt vmcnt(0)" ::: "memory");   // A done; vmcnt clean

    // staging roles: wave w stages mat = w>>1 (0=hi,1=lo), col-half ch = w&1
    const _Float16* const bsrc = (w < 2) ? enh : enl;
    const int dstoff = (w >> 1) * 8192 + (w & 1) * 4096;

    // per-lane incremental global pointer (chunk 0), bumped +CCH*DIM per stage
    const _Float16* gptr = bsrc + (size_t)(cbase + (w & 1) * 16 + (lane & 15)) * DIM + koff;

    float bestv[2][4];
    int   bestc[2][4];
#pragma unroll
    for (int i = 0; i < 2; ++i)
#pragma unroll
        for (int rg = 0; rg < 4; ++rg) { bestv[i][rg] = -2.0f; bestc[i][rg] = 0; }

    const f32x4 ZERO4 = (f32x4){0.f, 0.f, 0.f, 0.f};

    // prologue: chunk 0 in flight
    {
        _Float16* l0 = &smem[0][dstoff];
#pragma unroll
        for (int q = 0; q < 8; ++q)
            gload16(gptr + q * 32, l0 + q * 512);
        gptr += CCH * DIM;
    }

#pragma unroll 1
    for (int c = 0; c < NPH; ++c) {
        const int buf = c & 1;
        // publish chunk c: own loads drained BEFORE the barrier (per-wave vmcnt
        // is the only cross-wave visibility mechanism for global_load_lds).
        asm volatile("s_waitcnt vmcnt(0)" ::: "memory");
        __builtin_amdgcn_s_barrier();
        // stage chunk c+1 into the retired buffer (read finished last iter,
        // all waves past the barrier above). Full phase to cover latency.
        if (c + 1 < NPH) {
            _Float16* l0 = &smem[buf ^ 1][dstoff];
#pragma unroll
            for (int q = 0; q < 8; ++q)
                gload16(gptr + q * 32, l0 + q * 512);
            gptr += CCH * DIM;
        }

        const _Float16* bufp = &smem[buf][0];
        f32x4 acc0[2][2], acc1a[2][2], acc1b[2][2];   // [ch][i]

#pragma unroll
        for (int ch = 0; ch < 2; ++ch) {
#pragma unroll
            for (int kc = 0; kc < 8; ++kc) {
                const f16x8 Bh = *(const f16x8*)(bufp + (ch * 8 + kc) * 512 + lane * 8);
                const f16x8 Bl = *(const f16x8*)(bufp + 8192 + (ch * 8 + kc) * 512 + lane * 8);
                if (kc == 0) {
#pragma unroll
                    for (int i = 0; i < 2; ++i) {
                        acc0[ch][i]  = __builtin_amdgcn_mfma_f32_16x16x32_f16(Ah[i][0], Bh, ZERO4, 0, 0, 0);
                        acc1a[ch][i] = __builtin_amdgcn_mfma_f32_16x16x32_f16(Ah[i][0], Bl, ZERO4, 0, 0, 0);
                        acc1b[ch][i] = __builtin_amdgcn_mfma_f32_16x16x32_f16(Al[i][0], Bh, ZERO4, 0, 0, 0);
                    }
                } else {
#pragma unroll
                    for (int i = 0; i < 2; ++i) {
                        acc0[ch][i]  = __builtin_amdgcn_mfma_f32_16x16x32_f16(Ah[i][kc], Bh, acc0[ch][i],  0, 0, 0);
                        acc1a[ch][i] = __builtin_amdgcn_mfma_f32_16x16x32_f16(Ah[i][kc], Bl, acc1a[ch][i], 0, 0, 0);
                        acc1b[ch][i] = __builtin_amdgcn_mfma_f32_16x16x32_f16(Al[i][kc], Bh, acc1b[ch][i], 0, 0, 0);
                    }
                }
            }
        }

        // lane-local argmax: codes strictly increase per lane, so strict >
        // alone preserves first-occurrence semantics.
        const int cb = cbase + c * CCH;
#pragma unroll
        for (int ch = 0; ch < 2; ++ch)
#pragma unroll
            for (int i = 0; i < 2; ++i)
#pragma unroll
                for (int rg = 0; rg < 4; ++rg) {
                    const float vv = acc0[ch][i][rg] +
                        (acc1a[ch][i][rg] + acc1b[ch][i][rg]) * (1.0f / 2048.0f);
                    if (vv > bestv[i][rg]) { bestv[i][rg] = vv; bestc[i][rg] = cb + ch * 16; }
                }
    }

    // final cross-lane argmax (width 16), min-index tie-break
#pragma unroll
    for (int i = 0; i < 2; ++i)
#pragma unroll
        for (int rg = 0; rg < 4; ++rg) {
            float bv = bestv[i][rg];
            int bix = bestc[i][rg] + (lane & 15);
#pragma unroll
            for (int off = 1; off < 16; off <<= 1) {
                const float ov = __shfl_xor(bv, off, 16);
                const int oi = __shfl_xor(bix, off, 16);
                if (ov > bv || (ov == bv && oi < bix)) { bv = ov; bix = oi; }
            }
            if ((lane & 15) == 0) {
                const int r = rbase + w * 32 + i * 16 + (lane >> 4) * 4 + rg;
                cand_val[(size_t)r * NCAND + blockIdx.y] = bv;
                cand_idx[(size_t)r * NCAND + blockIdx.y] = bix;
            }
        }
}

// ---------- merge splits + gather quantize + scatter embed_sum ----------
__global__ __launch_bounds__(256) void k_merge(
    const float* __restrict__ x, const float* __restrict__ embed,
    const float* __restrict__ cand_val, const int* __restrict__ cand_idx,
    const float* __restrict__ xnorm,
    float* __restrict__ quantize, float* __restrict__ ind_out,
    float* __restrict__ embed_sum, float* __restrict__ bins)
{
    const int w = threadIdx.x >> 6, lane = threadIdx.x & 63;
    const int r = blockIdx.x * 4 + w;
    float v = -3e30f; int ix = 0x7fffffff;
    if (lane < NCAND) {
        v = cand_val[(size_t)r * NCAND + lane];
        ix = cand_idx[(size_t)r * NCAND + lane];
    }
#pragma unroll
    for (int off = 1; off < 8; off <<= 1) {
        const float ov = __shfl_xor(v, off, 8);
        const int oi = __shfl_xor(ix, off, 8);
        if (ov > v || (ov == v && oi < ix)) { v = ov; ix = oi; }
    }
    ix = __shfl(ix, 0, 64);
    if (lane == 0) {
        ind_out[r] = (float)ix;
        atomicAdd(&bins[ix], 1.0f);
    }
    f32x4 e = *(const f32x4*)&embed[(size_t)ix * DIM + lane * 4];
    *(f32x4*)&quantize[(size_t)r * DIM + lane * 4] = e;
    f32x4 xv = *(const f32x4*)&x[(size_t)r * DIM + lane * 4];
    const float n = xnorm[r];
    atomicAdd(&embed_sum[(size_t)ix * DIM + lane * 4 + 0], xv[0] / n);
    atomicAdd(&embed_sum[(size_t)ix * DIM + lane * 4 + 1], xv[1] / n);
    atomicAdd(&embed_sum[(size_t)ix * DIM + lane * 4 + 2], xv[2] / n);
    atomicAdd(&embed_sum[(size_t)ix * DIM + lane * 4 + 3], xv[3] / n);
}

// ---------- EMA update (en recomputed inline) ----------
__global__ __launch_bounds__(256) void k_update(const float* __restrict__ embed,
    const float* __restrict__ embed_sum, const float* __restrict__ bins,
    float* __restrict__ embed_new, int K)
{
    const int w = threadIdx.x >> 6, lane = threadIdx.x & 63;
    const int k = blockIdx.x * 4 + w;
    if (k >= K) return;
    f32x4 e = *(const f32x4*)&embed[(size_t)k * DIM + lane * 4];
    float sse = waveReduceSum(e[0]*e[0] + e[1]*e[1] + e[2]*e[2] + e[3]*e[3]);
    const float ne = fmaxf(sqrtf(sse), 1e-12f);

    const float b = bins[k];
    const float bs = (b == 0.f) ? 1.f : b;
    f32x4 s = *(const f32x4*)&embed_sum[(size_t)k * DIM + lane * 4];
    f32x4 vv;
    vv[0] = s[0] / bs; vv[1] = s[1] / bs; vv[2] = s[2] / bs; vv[3] = s[3] / bs;
    float ssv = waveReduceSum(vv[0]*vv[0] + vv[1]*vv[1] + vv[2]*vv[2] + vv[3]*vv[3]);
    const float nv = fmaxf(sqrtf(ssv), 1e-12f);

    f32x4 o;
#pragma unroll
    for (int c = 0; c < 4; ++c) {
        const float norm_c = (b == 0.f) ? (e[c] / ne) : (vv[c] / nv);
        o[c] = 0.8f * e[c] + 0.2f * norm_c;
    }
    *(f32x4*)&embed_new[(size_t)k * DIM + lane * 4] = o;
}

extern "C" void kernel_launch(void* const* d_in, const int* in_sizes, int n_in,
                              void* d_out, int out_size, void* d_ws, size_t ws_size,
                              hipStream_t stream) {
    const float* x = (const float*)d_in[0];
    const float* embed = (const float*)d_in[1];
    const int N = in_sizes[0] / DIM;   // 16384
    const int K = in_sizes[1] / DIM;   // 8192

    float* quantize  = (float*)d_out;
    float* ind_out   = quantize + (size_t)N * DIM;
    float* embed_new = ind_out + N;

    char* ws = (char*)d_ws;
    _Float16* fnh = (_Float16*)ws;                               // [0, 8M)
    _Float16* fnl = (_Float16*)(ws + (size_t)N * DIM * 2);       // [8M, 16M)
    _Float16* enh = (_Float16*)(ws + (size_t)N * DIM * 4);       // [16M, 20M)
    _Float16* enl = (_Float16*)(ws + (size_t)N * DIM * 4 + (size_t)K * DIM * 2);
    char* p = ws + (size_t)N * DIM * 4 + (size_t)K * DIM * 4;    // 24M
    float* xnorm    = (float*)p;                 p += (size_t)N * 4;
    float* cand_val = (float*)p;                 p += (size_t)N * NCAND * 4;
    int*   cand_idx = (int*)p;
    // embed_sum/bins alias fnh/fnl (dead after k_gemm)
    float* embed_sum = (float*)ws;               // K*DIM floats = 8 MB
    float* bins      = embed_sum + (size_t)K * DIM;

    k_prep<<<(N + 3) / 4, 256, 0, stream>>>(x, fnh, fnl, xnorm, N);
    k_prep<<<(K + 3) / 4, 256, 0, stream>>>(embed, enh, enl, nullptr, K);

    dim3 grid(N / NROWS_TILE, SPLITS);
    k_gemm<<<grid, 256, 0, stream>>>(fnh, fnl, enh, enl, cand_val, cand_idx);

    hipMemsetAsync(embed_sum, 0, ((size_t)K * DIM + K) * sizeof(float), stream);

    k_merge<<<(N + 3) / 4, 256, 0, stream>>>(x, embed, cand_val, cand_idx, xnorm,
                                             quantize, ind_out, embed_sum, bins);
    k_update<<<(K + 3) / 4, 256, 0, stream>>>(embed, embed_sum, bins, embed_new, K);
}